// Round 9
// baseline (171.394 us; speedup 1.0000x reference)
//
#include <hip/hip_runtime.h>
#include <hip/hip_bf16.h>

typedef float f4v __attribute__((ext_vector_type(4)));
typedef float f32x4 __attribute__((ext_vector_type(4)));
typedef __bf16 bf16x8 __attribute__((ext_vector_type(8)));

__device__ __forceinline__ unsigned pack2bf(float lo, float hi) {
  unsigned short ua = __builtin_bit_cast(unsigned short, (__bf16)lo);
  unsigned short ub = __builtin_bit_cast(unsigned short, (__bf16)hi);
  return (unsigned)ua | ((unsigned)ub << 16);
}

// ---------------- kernel 1: modulation MLP -> s [16][512] (f32, ws) -------
__global__ __launch_bounds__(256) void mlp_kernel(
    const float* __restrict__ t,
    const float* __restrict__ W1, const float* __restrict__ b1,
    const float* __restrict__ W2, const float* __restrict__ b2,
    const float* __restrict__ W3, const float* __restrict__ b3,
    float* __restrict__ s_out) {
  __shared__ float tt[256];
  __shared__ float hh[256];
  const int b = blockIdx.x;
  const int tid = threadIdx.x;
  tt[tid] = t[b * 256 + tid];
  __syncthreads();
  float acc = b1[tid];
  {
    const f4v* wrow = (const f4v*)(W1 + tid * 256);
    #pragma unroll 16
    for (int k = 0; k < 64; ++k) {
      f4v wv = wrow[k];
      acc += wv[0] * tt[4 * k] + wv[1] * tt[4 * k + 1] +
             wv[2] * tt[4 * k + 2] + wv[3] * tt[4 * k + 3];
    }
  }
  float h = acc / (1.0f + expf(-acc));
  __syncthreads();
  hh[tid] = h;
  __syncthreads();
  acc = b2[tid];
  {
    const f4v* wrow = (const f4v*)(W2 + tid * 256);
    #pragma unroll 16
    for (int k = 0; k < 64; ++k) {
      f4v wv = wrow[k];
      acc += wv[0] * hh[4 * k] + wv[1] * hh[4 * k + 1] +
             wv[2] * hh[4 * k + 2] + wv[3] * hh[4 * k + 3];
    }
  }
  h = acc / (1.0f + expf(-acc));
  __syncthreads();
  tt[tid] = h;
  __syncthreads();
  #pragma unroll
  for (int rep = 0; rep < 2; ++rep) {
    const int o = rep * 256 + tid;
    float a3 = b3[o];
    const f4v* wrow = (const f4v*)(W3 + o * 256);
    #pragma unroll 16
    for (int k = 0; k < 64; ++k) {
      f4v wv = wrow[k];
      a3 += wv[0] * tt[4 * k] + wv[1] * tt[4 * k + 1] +
            wv[2] * tt[4 * k + 2] + wv[3] * tt[4 * k + 3];
    }
    s_out[b * 512 + o] = a3 + 1.0f;
  }
}

// ---------------- kernel 2: demod + bw (bf16) [16][512][512] --------------
__global__ __launch_bounds__(256) void modw_kernel(
    const float* __restrict__ weight, const float* __restrict__ s_in,
    unsigned short* __restrict__ bwq) {
  const int tid = threadIdx.x;
  const int wid = (blockIdx.x << 2) | (tid >> 6);
  const int b = wid >> 9;
  const int o = wid & 511;
  const int lane = tid & 63;
  const f4v* wp = (const f4v*)(weight + o * 512 + lane * 8);
  const f4v* sp = (const f4v*)(s_in + b * 512 + lane * 8);
  f4v w0 = wp[0], w1 = wp[1];
  f4v s0 = sp[0], s1 = sp[1];
  float p[8];
  p[0] = w0[0] * s0[0]; p[1] = w0[1] * s0[1];
  p[2] = w0[2] * s0[2]; p[3] = w0[3] * s0[3];
  p[4] = w1[0] * s1[0]; p[5] = w1[1] * s1[1];
  p[6] = w1[2] * s1[2]; p[7] = w1[3] * s1[3];
  float ss = 0.0f;
  #pragma unroll
  for (int i = 0; i < 8; ++i) ss += p[i] * p[i];
  #pragma unroll
  for (int off = 32; off; off >>= 1) ss += __shfl_xor(ss, off);
  const float d = rsqrtf(ss + 1e-8f);
  uint4 outw;
  outw.x = pack2bf(p[0] * d, p[1] * d);
  outw.y = pack2bf(p[2] * d, p[3] * d);
  outw.z = pack2bf(p[4] * d, p[5] * d);
  outw.w = pack2bf(p[6] * d, p[7] * d);
  *(uint4*)(bwq + ((size_t)(b * 512 + o)) * 512 + lane * 8) = outw;
}

// ---------------- kernel 3: fused barrier-free GEMM out[b] = bw[b] @ x[b] -
// Per-wave autonomous: A-frags global->reg (bwq k-contig), x f32 global->reg
// (2-deep parity sets) -> pack bf16 into WAVE-PRIVATE LDS slab [64n][32k]
// (XOR swizzle s(n)=(n&3)<<3 on k: b128 reads 2-way-free, b64 writes ~2-way).
// ZERO barriers, ZERO manual waitcnt: all deps register-tracked by compiler.
// Latency hidden by 8 free-running waves/CU (TLP), not intra-wave schedule.
__global__ __launch_bounds__(256, 2) void gemm_kernel(
    const float* __restrict__ x, const unsigned short* __restrict__ bwq,
    float* __restrict__ out) {
  __shared__ __align__(16) unsigned short BsArr[2][4][2048];  // 32 KB

  const int bid = blockIdx.x;
  const int swz = ((bid & 7) << 8) | (bid >> 3);
  const int mt = swz & 3;            // mt innermost: 4 blocks share x panel
  const int nt = (swz >> 2) & 31;
  const int bb = swz >> 7;

  const int tid = threadIdx.x;
  const int lane = tid & 63;
  const int wv = tid >> 6;
  const int wr = wv >> 1, wc = wv & 1;

  const int rL = lane & 15;
  const int kqL = lane >> 4;   // 0..3
  const int q = lane & 15;     // x n-quad
  const int kb = lane >> 4;    // x k-block

  // x: lane covers n = q*4..+3, k = it*32 + kb*8 + j
  const float* xlane = x + ((size_t)bb * 512 + kb * 8) * 4096 +
                       nt * 128 + wc * 64 + q * 4;
  // A: lane reads frag rows mi*16+rL, k-contig 8 at kqL*8
  const unsigned short* abase =
      bwq + ((size_t)(bb * 512 + mt * 128 + wr * 64)) * 512;
  const unsigned short* aptr[4];
  #pragma unroll
  for (int mi = 0; mi < 4; ++mi)
    aptr[mi] = abase + (mi * 16 + rL) * 512 + kqL * 8;

  // B-frag read offsets (ushort): slab row n=ni*16+rL, swizzled k base
  int bro[4];
  #pragma unroll
  for (int ni = 0; ni < 4; ++ni)
    bro[ni] = (ni * 16 + rL) * 32 + ((kqL * 8) ^ ((rL & 3) * 8));

  f32x4 acc[4][4] = {};
  f4v xv[2][8];
  bf16x8 fv[2][4];

#define XLOAD(P, IT)                                                        \
  do {                                                                      \
    _Pragma("unroll")                                                       \
    for (int j = 0; j < 8; ++j)                                             \
      xv[P][j] = *(const f4v*)(xlane + ((size_t)((IT) * 32) + j) * 4096);   \
  } while (0)

#define ALOAD(P, IT)                                                        \
  do {                                                                      \
    _Pragma("unroll")                                                       \
    for (int mi = 0; mi < 4; ++mi)                                          \
      fv[P][mi] = *(const bf16x8*)(aptr[mi] + (IT) * 32);                   \
  } while (0)

#define PACK(P, BUF)                                                        \
  do {                                                                      \
    unsigned short* wbw = &BsArr[BUF][wv][0];                               \
    _Pragma("unroll")                                                       \
    for (int c = 0; c < 4; ++c) {                                           \
      _Pragma("unroll")                                                     \
      for (int h = 0; h < 2; ++h) {                                         \
        uint2 val;                                                          \
        val.x = pack2bf(xv[P][h * 4 + 0][c], xv[P][h * 4 + 1][c]);          \
        val.y = pack2bf(xv[P][h * 4 + 2][c], xv[P][h * 4 + 3][c]);          \
        *(uint2*)&wbw[(q * 4 + c) * 32 + ((kb * 8 + h * 4) ^ (c * 8))] = val; \
      }                                                                     \
    }                                                                       \
  } while (0)

#define COMPUTE(P, BUF)                                                     \
  do {                                                                      \
    const unsigned short* wb = &BsArr[BUF][wv][0];                          \
    bf16x8 b0 = *(const bf16x8*)(wb + bro[0]);                              \
    bf16x8 b1 = *(const bf16x8*)(wb + bro[1]);                              \
    bf16x8 b2 = *(const bf16x8*)(wb + bro[2]);                              \
    bf16x8 b3 = *(const bf16x8*)(wb + bro[3]);                              \
    acc[0][0] = __builtin_amdgcn_mfma_f32_16x16x32_bf16(fv[P][0], b0, acc[0][0], 0, 0, 0); \
    acc[0][1] = __builtin_amdgcn_mfma_f32_16x16x32_bf16(fv[P][0], b1, acc[0][1], 0, 0, 0); \
    acc[0][2] = __builtin_amdgcn_mfma_f32_16x16x32_bf16(fv[P][0], b2, acc[0][2], 0, 0, 0); \
    acc[0][3] = __builtin_amdgcn_mfma_f32_16x16x32_bf16(fv[P][0], b3, acc[0][3], 0, 0, 0); \
    acc[1][0] = __builtin_amdgcn_mfma_f32_16x16x32_bf16(fv[P][1], b0, acc[1][0], 0, 0, 0); \
    acc[1][1] = __builtin_amdgcn_mfma_f32_16x16x32_bf16(fv[P][1], b1, acc[1][1], 0, 0, 0); \
    acc[1][2] = __builtin_amdgcn_mfma_f32_16x16x32_bf16(fv[P][1], b2, acc[1][2], 0, 0, 0); \
    acc[1][3] = __builtin_amdgcn_mfma_f32_16x16x32_bf16(fv[P][1], b3, acc[1][3], 0, 0, 0); \
    acc[2][0] = __builtin_amdgcn_mfma_f32_16x16x32_bf16(fv[P][2], b0, acc[2][0], 0, 0, 0); \
    acc[2][1] = __builtin_amdgcn_mfma_f32_16x16x32_bf16(fv[P][2], b1, acc[2][1], 0, 0, 0); \
    acc[2][2] = __builtin_amdgcn_mfma_f32_16x16x32_bf16(fv[P][2], b2, acc[2][2], 0, 0, 0); \
    acc[2][3] = __builtin_amdgcn_mfma_f32_16x16x32_bf16(fv[P][2], b3, acc[2][3], 0, 0, 0); \
    acc[3][0] = __builtin_amdgcn_mfma_f32_16x16x32_bf16(fv[P][3], b0, acc[3][0], 0, 0, 0); \
    acc[3][1] = __builtin_amdgcn_mfma_f32_16x16x32_bf16(fv[P][3], b1, acc[3][1], 0, 0, 0); \
    acc[3][2] = __builtin_amdgcn_mfma_f32_16x16x32_bf16(fv[P][3], b2, acc[3][2], 0, 0, 0); \
    acc[3][3] = __builtin_amdgcn_mfma_f32_16x16x32_bf16(fv[P][3], b3, acc[3][3], 0, 0, 0); \
  } while (0)

  // STEP(IT, P=IT&1, Q=P^1): stage next A-frags + next-next x, pack next B,
  // compute current. All waits are compiler-inserted (register deps).
#define STEP(IT, P, Q)                                                      \
  do {                                                                      \
    if ((IT) + 1 < 16) ALOAD(Q, (IT) + 1);                                  \
    if ((IT) + 2 < 16) XLOAD(P, (IT) + 2);                                  \
    if ((IT) + 1 < 16) PACK(Q, ((IT) + 1) & 1);                             \
    COMPUTE(P, (IT) & 1);                                                   \
  } while (0)

  // prologue: x(0), x(1) in flight; A(0) in flight; B(0) packed (waits x0)
  XLOAD(0, 0);
  XLOAD(1, 1);
  ALOAD(0, 0);
  PACK(0, 0);

  STEP(0, 0, 1);  STEP(1, 1, 0);  STEP(2, 0, 1);  STEP(3, 1, 0);
  STEP(4, 0, 1);  STEP(5, 1, 0);  STEP(6, 0, 1);  STEP(7, 1, 0);
  STEP(8, 0, 1);  STEP(9, 1, 0);  STEP(10, 0, 1); STEP(11, 1, 0);
  STEP(12, 0, 1); STEP(13, 1, 0); STEP(14, 0, 1); STEP(15, 1, 0);

  // epilogue (verified mapping)
  const size_t ob =
      ((size_t)(bb * 512 + mt * 128 + wr * 64 + ((lane >> 4) << 2))) * 4096 +
      nt * 128 + wc * 64 + (lane & 15);
  #pragma unroll
  for (int mi = 0; mi < 4; ++mi)
    #pragma unroll
    for (int ni = 0; ni < 4; ++ni)
      #pragma unroll
      for (int jj = 0; jj < 4; ++jj)
        out[ob + (size_t)(mi * 16 + jj) * 4096 + ni * 16] = acc[mi][ni][jj];

#undef XLOAD
#undef ALOAD
#undef PACK
#undef COMPUTE
#undef STEP
}

extern "C" void kernel_launch(void* const* d_in, const int* in_sizes, int n_in,
                              void* d_out, int out_size, void* d_ws, size_t ws_size,
                              hipStream_t stream) {
  const float* x      = (const float*)d_in[0];
  const float* t      = (const float*)d_in[1];
  const float* weight = (const float*)d_in[2];
  const float* W1     = (const float*)d_in[3];
  const float* b1     = (const float*)d_in[4];
  const float* W2     = (const float*)d_in[5];
  const float* b2     = (const float*)d_in[6];
  const float* W3     = (const float*)d_in[7];
  const float* b3     = (const float*)d_in[8];
  float* out = (float*)d_out;

  float* s_ws = (float*)d_ws;                                   // 32 KB
  unsigned short* bwq = (unsigned short*)((char*)d_ws + 32 * 1024);  // 8 MB

  mlp_kernel<<<16, 256, 0, stream>>>(t, W1, b1, W2, b2, W3, b3, s_ws);
  modw_kernel<<<2048, 256, 0, stream>>>(weight, s_ws, bwq);
  gemm_kernel<<<2048, 256, 0, stream>>>(x, bwq, out);
}